// Round 14
// baseline (57.692 us; speedup 1.0000x reference)
//
#include <hip/hip_runtime.h>

// SSIM loss, fused. in: f32 (16,3,512,512) x2; out: f32[16].
//
// r14 = r13 column-slab structure with TWO INDEPENDENT CHAINS PER WAVE.
// Evidence: r13's L3-resident replays run at identical dur with ~0 HBM
// traffic -> latency-bound, not BW-bound; extra waves stopped helping
// (queueing). So hide latency with in-wave ILP/MLP: each wave processes
// the same (img, slab) at strips s and s+16 as two independent dependency
// chains. 8 global loads issue together per STEP; chain B's VALU work
// covers chain A's load latency within the wave.
//  * 48 img x 3 slab x 16 strip-pairs = 2304 single-wave blocks, XCD-
//    pinned img%8 (r10's proven FETCH fix). 8KB LDS (QA/QB).
//  * Per chain: 4 cols/lane vertical sliding sums {s1,s2,sp,sq} in regs;
//    NEW rows 3-deep register-pipelined (template-slot static indexing);
//    OLD row same-STEP (L1/L2); sigma-permuted wave-private LDS publish
//    (4x ds_write_b128) + 10x b128 halo reads, conflict-free; in-register
//    window slide; scale-folded SSIM; banked double atomics.

namespace {
constexpr int BATCH = 16;
constexpr int CHAN  = 3;
constexpr int HDIM  = 512;
constexpr int WDIM  = 512;
constexpr int WIN   = 11;
constexpr int HO    = HDIM - WIN + 1;   // 502
constexpr int WO    = WDIM - WIN + 1;   // 502
constexpr int RPS   = 16;
constexpr int NSTRIP = 32;              // strips; chainA: 0..15, chainB: 16..31
constexpr int SPAIR = 16;
constexpr int NSLAB = 3;
constexpr int NIMG  = BATCH * CHAN;     // 48
constexpr int NTHR  = 64;               // 1 wave per block
constexpr int NBLK  = NIMG * NSLAB * SPAIR;    // 2304
constexpr int NBANK = 16;
// scale-folded constants: C*121^2 (121^4 cancels in n/d)
constexpr float K1 = 6.5025f  * 14641.0f;
constexpr float K2 = 58.5225f * 14641.0f;
constexpr float W2F = 121.0f;
}

struct Chain {
  float s1[4], s2[4], sp[4], sq[4];
  float4 nA1, nA2, nB1, nB2, nC1, nC2;  // NEW 3-deep (slots 0,1,2)
  float4 o1, o2;                        // OLD
};

template<int S> __device__ __forceinline__ float4& bu(Chain& c) {
  if constexpr (S == 0) return c.nA1; else if constexpr (S == 1) return c.nB1;
  else return c.nC1;
}
template<int S> __device__ __forceinline__ float4& bv(Chain& c) {
  if constexpr (S == 0) return c.nA2; else if constexpr (S == 1) return c.nB2;
  else return c.nC2;
}

__device__ __forceinline__ void addrow(Chain& c, const float4& u, const float4& v) {
  float uu[4] = {u.x, u.y, u.z, u.w};
  float vv[4] = {v.x, v.y, v.z, v.w};
#pragma unroll
  for (int k = 0; k < 4; ++k) {
    float x = uu[k], y = vv[k];
    c.s1[k] += x;
    c.s2[k] += y;
    c.sp[k] = fmaf(x, y, c.sp[k]);
    c.sq[k] = fmaf(x, x, c.sq[k]);
    c.sq[k] = fmaf(y, y, c.sq[k]);
  }
}
__device__ __forceinline__ void subrow(Chain& c, const float4& u, const float4& v) {
  float uu[4] = {u.x, u.y, u.z, u.w};
  float vv[4] = {v.x, v.y, v.z, v.w};
#pragma unroll
  for (int k = 0; k < 4; ++k) {
    float x = uu[k], y = vv[k];
    c.s1[k] -= x;
    c.s2[k] -= y;
    c.sp[k] = fmaf(x, -y, c.sp[k]);
    c.sq[k] = fmaf(x, -x, c.sq[k]);
    c.sq[k] = fmaf(y, -y, c.sq[k]);
  }
}

template<int S> __device__ __forceinline__ void ldn(
    Chain& c, const float* __restrict__ p1, const float* __restrict__ p2, int row) {
  bu<S>(c) = *(const float4*)(p1 + (size_t)row * WDIM);
  bv<S>(c) = *(const float4*)(p2 + (size_t)row * WDIM);
}
template<int S> __device__ __forceinline__ void accn(Chain& c) {
  addrow(c, bu<S>(c), bv<S>(c));
}
__device__ __forceinline__ void ldo(
    Chain& c, const float* __restrict__ p1, const float* __restrict__ p2, int row) {
  c.o1 = *(const float4*)(p1 + (size_t)row * WDIM);
  c.o2 = *(const float4*)(p2 + (size_t)row * WDIM);
}
__device__ __forceinline__ void publish(const Chain& c, float4* Q, int t) {
#pragma unroll
  for (int i = 0; i < 4; ++i)
    Q[i * 64 + t] = make_float4(c.s1[i], c.s2[i], c.sp[i], c.sq[i]);
}
__device__ __forceinline__ void window(const Chain& c, const float4* Q, int t,
                                       int c0, int lo, int hi, float& accv) {
  float4 h[10];
#pragma unroll
  for (int m = 0; m < 10; ++m)
    h[m] = Q[(m & 3) * 64 + ((t + 1 + (m >> 2)) & 63)];

  float w1 = ((c.s1[0] + c.s1[1]) + (c.s1[2] + c.s1[3])) +
             ((h[0].x + h[1].x) + (h[2].x + h[3].x)) +
             ((h[4].x + h[5].x) + h[6].x);
  float w2 = ((c.s2[0] + c.s2[1]) + (c.s2[2] + c.s2[3])) +
             ((h[0].y + h[1].y) + (h[2].y + h[3].y)) +
             ((h[4].y + h[5].y) + h[6].y);
  float wp = ((c.sp[0] + c.sp[1]) + (c.sp[2] + c.sp[3])) +
             ((h[0].z + h[1].z) + (h[2].z + h[3].z)) +
             ((h[4].z + h[5].z) + h[6].z);
  float wq = ((c.sq[0] + c.sq[1]) + (c.sq[2] + c.sq[3])) +
             ((h[0].w + h[1].w) + (h[2].w + h[3].w)) +
             ((h[4].w + h[5].w) + h[6].w);

#pragma unroll
  for (int j = 0; j < 4; ++j) {
    if (j > 0) {
      w1 = (w1 - c.s1[j - 1]) + h[6 + j].x;
      w2 = (w2 - c.s2[j - 1]) + h[6 + j].y;
      wp = (wp - c.sp[j - 1]) + h[6 + j].z;
      wq = (wq - c.sq[j - 1]) + h[6 + j].w;
    }
    float s12 = w1 * w2;
    float msq = fmaf(w1, w1, w2 * w2);
    float N1_ = fmaf(2.f, s12, K1);
    float N2_ = fmaf(2.f, fmaf(W2F, wp, -s12), K2);
    float D1_ = msq + K1;
    float D2_ = fmaf(W2F, wq, -msq) + K2;
    float val = (N1_ * N2_) * __builtin_amdgcn_rcpf(D1_ * D2_);
    int cc = c0 + j;
    accv += (cc >= lo && cc <= hi) ? val : 0.f;
  }
}

__global__ __launch_bounds__(NTHR) void ssim_main(
    const float* __restrict__ g1, const float* __restrict__ g2,
    double* __restrict__ ws) {
  __shared__ float4 QA[256], QB[256];    // 8 KB

  const int t = threadIdx.x;             // lane 0..63
  // XCD-pinned decode: img%8 == blockIdx%8
  const int xcd   = blockIdx.x & 7;
  const int qq    = blockIdx.x >> 3;     // 0 .. 6*NSLAB*SPAIR-1
  const int g     = qq / (NSLAB * SPAIR);
  const int rem   = qq % (NSLAB * SPAIR);
  const int slab  = rem / SPAIR;
  const int spair = rem % SPAIR;
  const int img   = g * 8 + xcd;         // 0..47
  const int b     = img / CHAN;

  const int base = (slab == 0) ? 0 : (slab == 1 ? 244 : 256);
  const int lo   = (slab == 0) ? 0 : (slab == 1 ? 246 : 490);
  const int hi   = (slab == 0) ? 245 : (slab == 1 ? 489 : 501);

  const int r0a = spair * RPS;                 // strips 0..15: always 16 rows
  const int r0b = (spair + SPAIR) * RPS;       // strips 16..31
  const int r1b = min(r0b + RPS, HO);          // strip 31: 6 rows
  const int c0  = base + 4 * t;                // lane's first col (aligned)

  const float* __restrict__ p1 = g1 + (size_t)img * HDIM * WDIM + c0;
  const float* __restrict__ p2 = g2 + (size_t)img * HDIM * WDIM + c0;

  Chain A, B;
#pragma unroll
  for (int k = 0; k < 4; ++k) {
    A.s1[k] = A.s2[k] = A.sp[k] = A.sq[k] = 0.f;
    B.s1[k] = B.s2[k] = B.sp[k] = B.sq[k] = 0.f;
  }

  // ---- warm-up: rows r0..r0+9 accumulated, 3-deep, chains interleaved ----
  ldn<0>(A, p1, p2, r0a);     ldn<0>(B, p1, p2, r0b);
  ldn<1>(A, p1, p2, r0a + 1); ldn<1>(B, p1, p2, r0b + 1);
  ldn<2>(A, p1, p2, r0a + 2); ldn<2>(B, p1, p2, r0b + 2);
#define WSTEP(S, D)                                        \
  accn<S>(A); ldn<S>(A, p1, p2, r0a + (D));                \
  accn<S>(B); ldn<S>(B, p1, p2, r0b + (D));
  WSTEP(0, 3)  WSTEP(1, 4)  WSTEP(2, 5)
  WSTEP(0, 6)  WSTEP(1, 7)  WSTEP(2, 8)
  WSTEP(0, 9)  WSTEP(1, 10) WSTEP(2, 11)
  WSTEP(0, 12)
#undef WSTEP
  // accumulated rows r0..r0+9; bufs: slot1=+10, slot2=+11, slot0=+12

  float accv = 0.f;

#define STEP2(S, K)                                              \
  {                                                              \
    const int ra = r0a + (K);                                    \
    const int rb = r0b + (K);                                    \
    const bool doB = rb < r1b;                                   \
    accn<S>(A);                                                  \
    ldn<S>(A, p1, p2, min(ra + 13, HDIM - 1));                   \
    ldo(A, p1, p2, ra);                                          \
    if (doB) {                                                   \
      accn<S>(B);                                                \
      ldn<S>(B, p1, p2, min(rb + 13, HDIM - 1));                 \
      ldo(B, p1, p2, rb);                                        \
    }                                                            \
    publish(A, QA, t);                                           \
    if (doB) publish(B, QB, t);                                  \
    asm volatile("s_waitcnt lgkmcnt(0)" ::: "memory");           \
    window(A, QA, t, c0, lo, hi, accv);                          \
    subrow(A, A.o1, A.o2);                                       \
    if (doB) {                                                   \
      window(B, QB, t, c0, lo, hi, accv);                        \
      subrow(B, B.o1, B.o2);                                     \
    }                                                            \
  }

  // main loop: slots cycle [1,2,0] starting at k=0
  for (int k = 0; k < RPS; k += 3) {
    STEP2(1, k);
    if (k + 1 < RPS) STEP2(2, k + 1);
    if (k + 2 < RPS) STEP2(0, k + 2);
  }
#undef STEP2

  // wave reduction, banked double atomic (both chains same image -> same b)
#pragma unroll
  for (int off = 32; off > 0; off >>= 1) accv += __shfl_down(accv, off, 64);
  if (t == 0)
    atomicAdd(&ws[b * NBANK + (blockIdx.x & (NBANK - 1))], (double)accv);
}

__global__ void ssim_finalize(const double* __restrict__ ws,
                              float* __restrict__ out) {
  int i = threadIdx.x;
  if (i < BATCH) {
    double s = 0.0;
#pragma unroll
    for (int k = 0; k < NBANK; ++k) s += ws[i * NBANK + k];
    out[i] = (float)(1.0 - s / ((double)CHAN * HO * WO));
  }
}

extern "C" void kernel_launch(void* const* d_in, const int* in_sizes, int n_in,
                              void* d_out, int out_size, void* d_ws,
                              size_t ws_size, hipStream_t stream) {
  const float* img1 = (const float*)d_in[0];
  const float* img2 = (const float*)d_in[1];
  float* out = (float*)d_out;
  double* ws = (double*)d_ws;

  hipMemsetAsync(d_ws, 0, BATCH * NBANK * sizeof(double), stream);
  ssim_main<<<dim3(NBLK), NTHR, 0, stream>>>(img1, img2, ws);
  ssim_finalize<<<1, 64, 0, stream>>>(ws, out);
}

// Round 15
// 44.708 us; speedup vs baseline: 1.2904x; 1.2904x over previous
//
#include <hip/hip_runtime.h>

// SSIM loss, fused. in: f32 (16,3,512,512) x2; out: f32[16].
//
// r15: FULL-WIDTH wave, 8 cols/lane (64 lanes x 8 = 512 = image width).
// Kills r12-r14's 3-slab 1.5x load overlap AND cuts LDS ops/pixel 36%
// (18 b128 per 8 px vs 14 per 4 px). Pipe accounting at r13 geometry showed
// LDS ~20us, L1 ~11-16us, VALU ~18us per CU -- all three now shrink.
//  * Per lane: vertical sliding 11-row column sums {s1,s2,sp,sq} for its
//    8 cols in regs (32); NEW rows 3-deep (48 regs), OLD rows 2-deep (32),
//    all named slots, static indexing (no scratch).
//  * Per STEP: publish 8 col-quads to sigma-permuted wave-private LDS
//    (Q[i*64+t], conflict-free), 10 b128 halo reads, in-register window
//    slide, scale-folded SSIM, 8 outputs/lane.
//  * Grid: 48 img x 42 strips (RPS=12) = 2016 single-wave blocks,
//    XCD-pinned img%8; at ~180 VGPR -> 2 waves/SIMD = 8/CU -> entire grid
//    co-resident. 8KB LDS/block.
//  * Banked double atomics + finalize.

namespace {
constexpr int BATCH = 16;
constexpr int CHAN  = 3;
constexpr int HDIM  = 512;
constexpr int WDIM  = 512;
constexpr int WIN   = 11;
constexpr int HO    = HDIM - WIN + 1;   // 502
constexpr int WO    = WDIM - WIN + 1;   // 502
constexpr int RPS   = 12;
constexpr int NSTRIP = 42;              // 42*12=504 >= 502; strip41: 10 rows
constexpr int NIMG  = BATCH * CHAN;     // 48
constexpr int NTHR  = 64;               // 1 wave per block
constexpr int NBLK  = NIMG * NSTRIP;    // 2016
constexpr int NBANK = 16;
// scale-folded constants: C*121^2 (121^4 cancels in n/d)
constexpr float K1 = 6.5025f  * 14641.0f;
constexpr float K2 = 58.5225f * 14641.0f;
constexpr float W2F = 121.0f;
}

__global__ __launch_bounds__(NTHR) void ssim_main(
    const float* __restrict__ g1, const float* __restrict__ g2,
    double* __restrict__ ws) {
  __shared__ float4 Q[512];              // 8 KB: 8 quads x 64 lanes

  const int t = threadIdx.x;             // lane 0..63
  // XCD-pinned decode: img%8 == blockIdx%8; band-major within XCD
  const int xcd   = blockIdx.x & 7;
  const int q     = blockIdx.x >> 3;     // 0..251
  const int g     = q % (NIMG / 8);      // 0..5
  const int strip = q / (NIMG / 8);      // 0..41
  const int img   = g * 8 + xcd;         // 0..47
  const int b     = img / CHAN;

  const int r0 = strip * RPS;
  const int r1 = min(r0 + RPS, HO);
  const int c0 = 8 * t;                  // lane's first col
  const int tp1 = (t + 1) & 63;          // halo lanes (wrap -> masked outputs)
  const int tp2 = (t + 2) & 63;

  const float* __restrict__ p1 = g1 + (size_t)img * HDIM * WDIM + c0;
  const float* __restrict__ p2 = g2 + (size_t)img * HDIM * WDIM + c0;

  // vertical sliding column sums for the lane's 8 columns
  float s1[8], s2[8], sp[8], sq[8];
#pragma unroll
  for (int k = 0; k < 8; ++k) s1[k] = s2[k] = sp[k] = sq[k] = 0.f;

  // named row-buffer slots: NEW 3-deep (n0,n1,n2), OLD 2-deep (o0,o1)
#define DECL_SLOT(p) float4 p##u0, p##u1, p##v0, p##v1;
  DECL_SLOT(n0) DECL_SLOT(n1) DECL_SLOT(n2) DECL_SLOT(o0) DECL_SLOT(o1)

#define LD(p, row)                                          \
  {                                                         \
    const float* q1_ = p1 + (size_t)(row) * WDIM;           \
    const float* q2_ = p2 + (size_t)(row) * WDIM;           \
    p##u0 = *(const float4*)q1_;                            \
    p##u1 = *(const float4*)(q1_ + 4);                      \
    p##v0 = *(const float4*)q2_;                            \
    p##v1 = *(const float4*)(q2_ + 4);                      \
  }

#define ACC8(p)                                                          \
  {                                                                      \
    float uu[8] = {p##u0.x, p##u0.y, p##u0.z, p##u0.w,                   \
                   p##u1.x, p##u1.y, p##u1.z, p##u1.w};                  \
    float vv[8] = {p##v0.x, p##v0.y, p##v0.z, p##v0.w,                   \
                   p##v1.x, p##v1.y, p##v1.z, p##v1.w};                  \
    _Pragma("unroll") for (int k_ = 0; k_ < 8; ++k_) {                   \
      float x = uu[k_], y = vv[k_];                                      \
      s1[k_] += x;                                                       \
      s2[k_] += y;                                                       \
      sp[k_] = fmaf(x, y, sp[k_]);                                       \
      sq[k_] = fmaf(x, x, sq[k_]);                                       \
      sq[k_] = fmaf(y, y, sq[k_]);                                       \
    }                                                                    \
  }

#define SUB8(p)                                                          \
  {                                                                      \
    float uu[8] = {p##u0.x, p##u0.y, p##u0.z, p##u0.w,                   \
                   p##u1.x, p##u1.y, p##u1.z, p##u1.w};                  \
    float vv[8] = {p##v0.x, p##v0.y, p##v0.z, p##v0.w,                   \
                   p##v1.x, p##v1.y, p##v1.z, p##v1.w};                  \
    _Pragma("unroll") for (int k_ = 0; k_ < 8; ++k_) {                   \
      float x = uu[k_], y = vv[k_];                                      \
      s1[k_] -= x;                                                       \
      s2[k_] -= y;                                                       \
      sp[k_] = fmaf(x, -y, sp[k_]);                                      \
      sq[k_] = fmaf(x, -x, sq[k_]);                                      \
      sq[k_] = fmaf(y, -y, sq[k_]);                                      \
    }                                                                    \
  }

  // ---- warm-up: accumulate rows r0..r0+9, 3-deep pipeline ----
  LD(n0, r0) LD(n1, r0 + 1) LD(n2, r0 + 2)
  ACC8(n0) LD(n0, r0 + 3)
  ACC8(n1) LD(n1, r0 + 4)
  ACC8(n2) LD(n2, r0 + 5)
  ACC8(n0) LD(n0, r0 + 6)
  ACC8(n1) LD(n1, r0 + 7)
  ACC8(n2) LD(n2, r0 + 8)
  ACC8(n0) LD(n0, r0 + 9)
  ACC8(n1) LD(n1, r0 + 10)
  ACC8(n2) LD(n2, r0 + 11)
  ACC8(n0) LD(n0, r0 + 12)
  // accumulated rows r0..r0+9; n1=r0+10, n2=r0+11, n0=r0+12
  LD(o0, r0) LD(o1, r0 + 1)   // OLD 2-deep

  float acc = 0.f;

  // one STEP: NEW slot pn holds row r+10; OLD slot po holds row r.
#define DOSTEP(pn, po, r_)                                               \
  {                                                                      \
    const int rr = (r_);                                                 \
    ACC8(pn)                            /* window = rows [rr, rr+10] */  \
    LD(pn, min(rr + 13, HDIM - 1))      /* NEW for STEP rr+3 */          \
    _Pragma("unroll") for (int i_ = 0; i_ < 8; ++i_)                     \
        Q[i_ * 64 + t] = make_float4(s1[i_], s2[i_], sp[i_], sq[i_]);    \
    asm volatile("s_waitcnt lgkmcnt(0)" ::: "memory");                   \
    float4 h[10];                                                        \
    _Pragma("unroll") for (int m_ = 0; m_ < 8; ++m_)                     \
        h[m_] = Q[m_ * 64 + tp1];                                        \
    h[8] = Q[tp2];                                                       \
    h[9] = Q[64 + tp2];                                                  \
    float w1 = ((s1[0] + s1[1]) + (s1[2] + s1[3])) +                     \
               ((s1[4] + s1[5]) + (s1[6] + s1[7])) +                     \
               ((h[0].x + h[1].x) + h[2].x);                             \
    float w2 = ((s2[0] + s2[1]) + (s2[2] + s2[3])) +                     \
               ((s2[4] + s2[5]) + (s2[6] + s2[7])) +                     \
               ((h[0].y + h[1].y) + h[2].y);                             \
    float wp = ((sp[0] + sp[1]) + (sp[2] + sp[3])) +                     \
               ((sp[4] + sp[5]) + (sp[6] + sp[7])) +                     \
               ((h[0].z + h[1].z) + h[2].z);                             \
    float wq = ((sq[0] + sq[1]) + (sq[2] + sq[3])) +                     \
               ((sq[4] + sq[5]) + (sq[6] + sq[7])) +                     \
               ((h[0].w + h[1].w) + h[2].w);                             \
    _Pragma("unroll") for (int j_ = 0; j_ < 8; ++j_) {                   \
      if (j_ > 0) {                                                      \
        w1 = (w1 - s1[j_ - 1]) + h[j_ + 2].x;                            \
        w2 = (w2 - s2[j_ - 1]) + h[j_ + 2].y;                            \
        wp = (wp - sp[j_ - 1]) + h[j_ + 2].z;                            \
        wq = (wq - sq[j_ - 1]) + h[j_ + 2].w;                            \
      }                                                                  \
      float s12 = w1 * w2;                                               \
      float msq = fmaf(w1, w1, w2 * w2);                                 \
      float N1_ = fmaf(2.f, s12, K1);                                    \
      float N2_ = fmaf(2.f, fmaf(W2F, wp, -s12), K2);                    \
      float D1_ = msq + K1;                                              \
      float D2_ = fmaf(W2F, wq, -msq) + K2;                              \
      float val = (N1_ * N2_) * __builtin_amdgcn_rcpf(D1_ * D2_);        \
      acc += (c0 + j_ < WO) ? val : 0.f;                                 \
    }                                                                    \
    SUB8(po)                            /* remove row rr */              \
    LD(po, rr + 2)                      /* OLD for STEP rr+2 (<=503) */  \
  }

  // main loop: NEW slot cycles (k+1)%3 -> n1,n2,n0,...; OLD k%2 -> o0,o1
  for (int k = 0; k < RPS; k += 6) {
    const int r = r0 + k;
    if (r     < r1) DOSTEP(n1, o0, r)
    if (r + 1 < r1) DOSTEP(n2, o1, r + 1)
    if (r + 2 < r1) DOSTEP(n0, o0, r + 2)
    if (r + 3 < r1) DOSTEP(n1, o1, r + 3)
    if (r + 4 < r1) DOSTEP(n2, o0, r + 4)
    if (r + 5 < r1) DOSTEP(n0, o1, r + 5)
  }
#undef DOSTEP
#undef SUB8
#undef ACC8
#undef LD
#undef DECL_SLOT

  // wave reduction, banked double atomic
#pragma unroll
  for (int off = 32; off > 0; off >>= 1) acc += __shfl_down(acc, off, 64);
  if (t == 0)
    atomicAdd(&ws[b * NBANK + (blockIdx.x & (NBANK - 1))], (double)acc);
}

__global__ void ssim_finalize(const double* __restrict__ ws,
                              float* __restrict__ out) {
  int i = threadIdx.x;
  if (i < BATCH) {
    double s = 0.0;
#pragma unroll
    for (int k = 0; k < NBANK; ++k) s += ws[i * NBANK + k];
    out[i] = (float)(1.0 - s / ((double)CHAN * HO * WO));
  }
}

extern "C" void kernel_launch(void* const* d_in, const int* in_sizes, int n_in,
                              void* d_out, int out_size, void* d_ws,
                              size_t ws_size, hipStream_t stream) {
  const float* img1 = (const float*)d_in[0];
  const float* img2 = (const float*)d_in[1];
  float* out = (float*)d_out;
  double* ws = (double*)d_ws;

  hipMemsetAsync(d_ws, 0, BATCH * NBANK * sizeof(double), stream);
  ssim_main<<<dim3(NBLK), NTHR, 0, stream>>>(img1, img2, ws);
  ssim_finalize<<<1, 64, 0, stream>>>(ws, out);
}